// Round 14
// baseline (452.997 us; speedup 1.0000x reference)
//
#include <hip/hip_runtime.h>

#define N_NODES 50000
#define N_EDGES 800000
#define D 128
#define NGROUPS 3125   // N_NODES / 16
#define NBUK 256       // node buckets
#define NPB 196        // nodes per bucket (256*196 = 50176 >= 50001)
#define EPB 4096       // edges per hist/scatter vblock (16 per thread)
#define NBLK 196       // ceil(N_EDGES / EPB)
#define LTOT (NBUK * NBLK)  // 50176 scan cells
#define GRID_CSR 960   // co-resident at 4 blocks/CU (launch_bounds 256,4)

typedef __attribute__((ext_vector_type(8))) short short8;
typedef __attribute__((ext_vector_type(4))) float f32x4;

__device__ __forceinline__ float bits2f(unsigned int u) {
    union { unsigned int u; float f; } c; c.u = u; return c.f;
}
__device__ __forceinline__ unsigned short f2b(float f) {
    union { float f; unsigned int u; } c; c.f = f;
    unsigned int r = c.u + 0x7fffu + ((c.u >> 16) & 1u);
    return (unsigned short)(r >> 16);
}

// software grid barrier: all gridDim.x blocks co-resident (guaranteed by
// launch_bounds + GRID_CSR <= 4 blocks/CU * 256 CU). Device-scope atomics.
__device__ __forceinline__ void gbar(int* bar, int idx) {
    __syncthreads();
    if (threadIdx.x == 0) {
        __threadfence();
        atomicAdd(&bar[idx], 1);
        while (atomicAdd(&bar[idx], 0) < (int)gridDim.x)
            __builtin_amdgcn_s_sleep(8);
        __threadfence();
    }
    __syncthreads();
}

// exclusive 256-scan within a block (wave shfl + 4 wave sums)
__device__ __forceinline__ int scan256(int v, int* wsum) {
    __syncthreads();  // protect wsum reuse across calls
    int lane = threadIdx.x & 63, wid = threadIdx.x >> 6;
    int s = v;
    #pragma unroll
    for (int off = 1; off < 64; off <<= 1) {
        int t = __shfl_up(s, off, 64);
        if (lane >= off) s += t;
    }
    if (lane == 63) wsum[wid] = s;
    __syncthreads();
    if (threadIdx.x == 0) {
        int r = 0;
        #pragma unroll
        for (int k = 0; k < 4; ++k) { int t = wsum[k]; wsum[k] = r; r += t; }
    }
    __syncthreads();
    return s - v + wsum[wid];
}

// ---- mega kernel: CSR build (LDS counting sort, grid-barriered) + setup --
// H:  LDS 256-bucket histogram of dst -> cnt[vb][bucket]
// S1: block-scan cells (bucket-major) -> scC + psum partials
// S2: scan psum (196)
// SC: LDS-cursor scatter -> epair (int2{dst,src}) bucket-grouped
// BK: per-bucket count/scan -> rs, col
// tail (no barrier): cast x->f0 | pack W0,W1 | pad row | u,v,c

__global__ __launch_bounds__(256, 4) void k_mega(
    const int* __restrict__ src, const int* __restrict__ dst,
    int* __restrict__ bar, int* __restrict__ cnt, int* __restrict__ scC,
    int* __restrict__ psum, int2* __restrict__ epair,
    int* __restrict__ rs, int* __restrict__ col,
    const float* __restrict__ x,
    const float* __restrict__ wn0, const float* __restrict__ wr0,
    const float* __restrict__ wn1, const float* __restrict__ wr1,
    const float* __restrict__ wn2, const float* __restrict__ wr2,
    const float* __restrict__ b2, const float* __restrict__ wc,
    const float* __restrict__ bc,
    unsigned short* __restrict__ f0, unsigned short* __restrict__ f1,
    unsigned short* __restrict__ f2, unsigned short* __restrict__ Bp,
    float* __restrict__ uvc) {
    __shared__ int lc[NBUK];
    __shared__ int wsum[4];
    __shared__ int cur[NBUK];
    const int b = blockIdx.x;
    const int tid = threadIdx.x;
    const int grid = gridDim.x;

    // ---- H: histogram ----
    if (b < NBLK) {
        lc[tid] = 0;
        __syncthreads();
        #pragma unroll
        for (int k = 0; k < 16; ++k) {
            int e = b * EPB + k * 256 + tid;
            if (e < N_EDGES) atomicAdd(&lc[dst[e] / NPB], 1);  // LDS atomic
        }
        __syncthreads();
        cnt[b * NBUK + tid] = lc[tid];
    }
    gbar(bar, 0);

    // ---- S1: block-scan of cells in bucket-major order ----
    if (b < NBLK) {
        int C = b * 256 + tid;          // cell id, C < LTOT
        int bkt = C / NBLK, j = C - bkt * NBLK;
        int v = cnt[j * NBUK + bkt];
        int excl = scan256(v, wsum);
        scC[C] = excl;
        if (tid == 255) psum[b] = excl + v;
    }
    gbar(bar, 1);

    // ---- S2: scan the 196 partials ----
    if (b == 0) {
        int v = (tid < NBLK) ? psum[tid] : 0;
        int excl = scan256(v, wsum);
        if (tid < NBLK) psum[tid] = excl;
    }
    gbar(bar, 2);

    // ---- SC: scatter edges bucket-grouped via LDS cursors ----
    if (b < NBLK) {
        int C = tid * NBLK + b;         // cell (bucket=tid, block=b)
        cur[tid] = scC[C] + psum[C >> 8];
        __syncthreads();
        #pragma unroll
        for (int k = 0; k < 16; ++k) {
            int e = b * EPB + k * 256 + tid;
            if (e < N_EDGES) {
                int d = dst[e];
                int p = atomicAdd(&cur[d / NPB], 1);  // LDS atomic
                epair[p] = make_int2(d, src[e]);
            }
        }
    }
    gbar(bar, 3);

    // ---- BK: per-bucket rank + rs + final col ----
    if (b < NBUK) {
        int C0 = b * NBLK;
        int gs = scC[C0] + psum[C0 >> 8];
        int be = N_EDGES;
        if (b + 1 < NBUK) {
            int C1 = (b + 1) * NBLK;
            be = scC[C1] + psum[C1 >> 8];
        }
        lc[tid] = 0;   // reuse lc as lcnt
        __syncthreads();
        for (int e = gs + tid; e < be; e += 256)
            atomicAdd(&lc[epair[e].x - b * NPB], 1);  // LDS atomic
        __syncthreads();
        int v = (tid < NPB) ? lc[tid] : 0;
        int excl = scan256(v, wsum);
        int node = b * NPB + tid;
        if (tid < NPB && node <= N_NODES) rs[node] = gs + excl;
        cur[tid] = gs + excl;
        __syncthreads();
        for (int e = gs + tid; e < be; e += 256) {
            int2 p2 = epair[e];
            int p = atomicAdd(&cur[p2.x - b * NPB], 1);  // LDS atomic
            col[p] = p2.y;
        }
        if (b == NBUK - 1 && tid == 0) rs[N_NODES] = N_EDGES;
    }

    // ---- tail: cast | pack | pad | uvc (independent outputs, no barrier) --
    for (int vb = b; vb < 6250; vb += grid) {
        int i = vb * 256 + tid;
        float4 v = reinterpret_cast<const float4*>(x)[i];
        ushort4 o;
        o.x = f2b(v.x); o.y = f2b(v.y); o.z = f2b(v.z); o.w = f2b(v.w);
        reinterpret_cast<ushort4*>(f0)[i] = o;
    }
    for (int vb = b; vb < 32; vb += grid) {
        int t = vb * 256 + tid;          // < 8192 = 2*8*8*64
        int layer = t >> 12;
        int rem = t & 4095;
        int kstep = rem >> 9;
        int cf = (rem >> 6) & 7;
        int lane = t & 63;
        const float* W = (kstep < 4) ? (layer ? wn1 : wn0) : (layer ? wr1 : wr0);
        int kb = kstep * 32 + (lane >> 4) * 8;
        int colv = cf * 16 + (lane & 15);
        int koff = (kstep < 4) ? kb : kb - 128;
        unsigned short* dstp = Bp + (((layer * 64 + kstep * 8 + cf) * 64 + lane) << 3);
        #pragma unroll
        for (int i = 0; i < 8; ++i) dstp[i] = f2b(W[(koff + i) * D + colv]);
    }
    if (b == grid - 1) {
        if (tid < D) {
            f0[(size_t)N_NODES * D + tid] = 0;
            f1[(size_t)N_NODES * D + tid] = 0;
            f2[(size_t)N_NODES * D + tid] = 0;
        }
    }
    if (b == grid - 2) {
        if (tid < 128) {
            float su = 0.f;
            for (int m = 0; m < 128; ++m) su += wn2[tid * D + m] * wc[m];
            uvc[tid] = su;
        } else {
            int k = tid - 128;
            float sv = 0.f;
            for (int m = 0; m < 128; ++m) sv += wr2[k * D + m] * wc[m];
            uvc[128 + k] = sv;
        }
        if (tid == 0) {
            float sc0 = 0.f;
            for (int m = 0; m < 128; ++m) sc0 += b2[m] * wc[m];
            uvc[256] = sc0 + bc[0];
        }
    }
}

// ---------------- mean aggregation: one node per wave (validated r8) ------

#define ACCUM(v)                                                      \
    acc0 += bits2f((v).x << 16); acc1 += bits2f((v).x & 0xffff0000u); \
    acc2 += bits2f((v).y << 16); acc3 += bits2f((v).y & 0xffff0000u); \
    acc4 += bits2f((v).z << 16); acc5 += bits2f((v).z & 0xffff0000u); \
    acc6 += bits2f((v).w << 16); acc7 += bits2f((v).w & 0xffff0000u);

__global__ __launch_bounds__(256) void k_agg2(const unsigned short* __restrict__ h,
                                              const int* __restrict__ rs,
                                              const int* __restrict__ col,
                                              unsigned short* __restrict__ mean) {
    const int lane = threadIdx.x & 63;
    const int node = blockIdx.x * 4 + (threadIdx.x >> 6);
    if (node >= N_NODES) return;
    const int j0 = rs[node], j1 = rs[node + 1];
    const int deg = j1 - j0;
    const int q = lane >> 4;
    const int d8 = (lane & 15) * 8;

    int myc = (j0 + lane < j1) ? col[j0 + lane] : N_NODES;  // pad row: zeros
    const int nfull = deg < 64 ? deg : 64;
    const int nb = (nfull + 15) >> 4;   // wave-uniform batch count

    float acc0 = 0.f, acc1 = 0.f, acc2 = 0.f, acc3 = 0.f;
    float acc4 = 0.f, acc5 = 0.f, acc6 = 0.f, acc7 = 0.f;

    for (int i = 0; i < nb; ++i) {      // uniform trips: shfl always safe
        int t = (i << 4) + q;
        int c0 = __shfl(myc, t, 64);
        int c1 = __shfl(myc, t + 4, 64);
        int c2 = __shfl(myc, t + 8, 64);
        int c3 = __shfl(myc, t + 12, 64);
        uint4 v0 = *(const uint4*)(h + (size_t)c0 * D + d8);
        uint4 v1 = *(const uint4*)(h + (size_t)c1 * D + d8);
        uint4 v2 = *(const uint4*)(h + (size_t)c2 * D + d8);
        uint4 v3 = *(const uint4*)(h + (size_t)c3 * D + d8);
        ACCUM(v0); ACCUM(v1); ACCUM(v2); ACCUM(v3);
    }
    for (int j = j0 + 64 + q; j < j1; j += 4) {  // deg>64 (~never); no shfl
        int c = col[j];
        uint4 v = *(const uint4*)(h + (size_t)c * D + d8);
        ACCUM(v);
    }

    acc0 += __shfl_xor(acc0, 16, 64); acc0 += __shfl_xor(acc0, 32, 64);
    acc1 += __shfl_xor(acc1, 16, 64); acc1 += __shfl_xor(acc1, 32, 64);
    acc2 += __shfl_xor(acc2, 16, 64); acc2 += __shfl_xor(acc2, 32, 64);
    acc3 += __shfl_xor(acc3, 16, 64); acc3 += __shfl_xor(acc3, 32, 64);
    acc4 += __shfl_xor(acc4, 16, 64); acc4 += __shfl_xor(acc4, 32, 64);
    acc5 += __shfl_xor(acc5, 16, 64); acc5 += __shfl_xor(acc5, 32, 64);
    acc6 += __shfl_xor(acc6, 16, 64); acc6 += __shfl_xor(acc6, 32, 64);
    acc7 += __shfl_xor(acc7, 16, 64); acc7 += __shfl_xor(acc7, 32, 64);

    if (lane < 16) {
        float s = 1.0f / (float)(deg > 0 ? deg : 1);
        uint4 o;
        o.x = (unsigned int)f2b(acc0 * s) | ((unsigned int)f2b(acc1 * s) << 16);
        o.y = (unsigned int)f2b(acc2 * s) | ((unsigned int)f2b(acc3 * s) << 16);
        o.z = (unsigned int)f2b(acc4 * s) | ((unsigned int)f2b(acc5 * s) << 16);
        o.w = (unsigned int)f2b(acc6 * s) | ((unsigned int)f2b(acc7 * s) << 16);
        *reinterpret_cast<uint4*>(mean + (size_t)node * D + d8) = o;
    }
}

// ---------------- MFMA GEMM (relu, layer 0): 2 row-groups per wave --------

__global__ __launch_bounds__(256) void k_gemm(
    const unsigned short* __restrict__ Amean, const unsigned short* __restrict__ Ah,
    const unsigned short* __restrict__ Bp, const float* __restrict__ bias,
    unsigned short* __restrict__ outh) {
    int lane = threadIdx.x & 63;
    int w = blockIdx.x * 4 + (threadIdx.x >> 6);
    int g0 = w * 2;
    if (g0 >= NGROUPS) return;
    int g1ok = (g0 + 1 < NGROUPS);
    int hl = lane & 15;
    int klane = (lane >> 4) * 8;
    int arow0 = g0 * 16 + hl;
    int arow1 = g0 * 16 + 16 + hl;
    if (arow1 > N_NODES) arow1 = N_NODES;  // pad row (zeros) when g1 invalid

    f32x4 acc0[8], acc1[8];
    #pragma unroll
    for (int i = 0; i < 8; ++i) { acc0[i] = (f32x4)0.0f; acc1[i] = (f32x4)0.0f; }

    const short8* bpv = reinterpret_cast<const short8*>(Bp);
    #pragma unroll
    for (int kstep = 0; kstep < 8; ++kstep) {
        const unsigned short* Asrc = (kstep < 4) ? Amean : Ah;
        int kk = (kstep & 3) * 32 + klane;
        short8 a0 = *reinterpret_cast<const short8*>(Asrc + (size_t)arow0 * D + kk);
        short8 a1 = *reinterpret_cast<const short8*>(Asrc + (size_t)arow1 * D + kk);
        #pragma unroll
        for (int cf = 0; cf < 8; ++cf) {
            short8 b = bpv[(kstep * 8 + cf) * 64 + lane];
            acc0[cf] = __builtin_amdgcn_mfma_f32_16x16x32_bf16(a0, b, acc0[cf], 0, 0, 0);
            acc1[cf] = __builtin_amdgcn_mfma_f32_16x16x32_bf16(a1, b, acc1[cf], 0, 0, 0);
        }
    }

    int rbase0 = g0 * 16 + (lane >> 4) * 4;
    #pragma unroll
    for (int cf = 0; cf < 8; ++cf) {
        int bcol = cf * 16 + hl;
        float bv = bias[bcol];
        #pragma unroll
        for (int i = 0; i < 4; ++i) {
            float v = fmaxf(acc0[cf][i] + bv, 0.f);
            outh[(size_t)(rbase0 + i) * D + bcol] = f2b(v);
            if (g1ok) {
                float v1 = fmaxf(acc1[cf][i] + bv, 0.f);
                outh[(size_t)(rbase0 + 16 + i) * D + bcol] = f2b(v1);
            }
        }
    }
}

// ---- MFMA GEMM layer 1 + fused dot: s = relu(row).u, t = relu(row).v -----

__global__ __launch_bounds__(256) void k_gemm_dot(
    const unsigned short* __restrict__ Amean, const unsigned short* __restrict__ Ah,
    const unsigned short* __restrict__ Bp, const float* __restrict__ bias,
    const float* __restrict__ uvc, float* __restrict__ s, float* __restrict__ t) {
    int lane = threadIdx.x & 63;
    int w = blockIdx.x * 4 + (threadIdx.x >> 6);
    int g0 = w * 2;
    if (g0 >= NGROUPS) return;
    int g1ok = (g0 + 1 < NGROUPS);
    int hl = lane & 15;
    int klane = (lane >> 4) * 8;
    int arow0 = g0 * 16 + hl;
    int arow1 = g0 * 16 + 16 + hl;
    if (arow1 > N_NODES) arow1 = N_NODES;

    f32x4 acc0[8], acc1[8];
    #pragma unroll
    for (int i = 0; i < 8; ++i) { acc0[i] = (f32x4)0.0f; acc1[i] = (f32x4)0.0f; }

    const short8* bpv = reinterpret_cast<const short8*>(Bp);
    #pragma unroll
    for (int kstep = 0; kstep < 8; ++kstep) {
        const unsigned short* Asrc = (kstep < 4) ? Amean : Ah;
        int kk = (kstep & 3) * 32 + klane;
        short8 a0 = *reinterpret_cast<const short8*>(Asrc + (size_t)arow0 * D + kk);
        short8 a1 = *reinterpret_cast<const short8*>(Asrc + (size_t)arow1 * D + kk);
        #pragma unroll
        for (int cf = 0; cf < 8; ++cf) {
            short8 b = bpv[(kstep * 8 + cf) * 64 + lane];
            acc0[cf] = __builtin_amdgcn_mfma_f32_16x16x32_bf16(a0, b, acc0[cf], 0, 0, 0);
            acc1[cf] = __builtin_amdgcn_mfma_f32_16x16x32_bf16(a1, b, acc1[cf], 0, 0, 0);
        }
    }

    float ps0[4] = {0.f, 0.f, 0.f, 0.f}, pt0[4] = {0.f, 0.f, 0.f, 0.f};
    float ps1[4] = {0.f, 0.f, 0.f, 0.f}, pt1[4] = {0.f, 0.f, 0.f, 0.f};
    #pragma unroll
    for (int cf = 0; cf < 8; ++cf) {
        int bcol = cf * 16 + hl;
        float bv = bias[bcol];
        float uu = uvc[bcol];
        float vv = uvc[128 + bcol];
        #pragma unroll
        for (int i = 0; i < 4; ++i) {
            float v = fmaxf(acc0[cf][i] + bv, 0.f);
            ps0[i] += v * uu;
            pt0[i] += v * vv;
            float v1 = fmaxf(acc1[cf][i] + bv, 0.f);
            ps1[i] += v1 * uu;
            pt1[i] += v1 * vv;
        }
    }
    #pragma unroll
    for (int m = 1; m < 16; m <<= 1) {
        #pragma unroll
        for (int i = 0; i < 4; ++i) {
            ps0[i] += __shfl_xor(ps0[i], m, 64);
            pt0[i] += __shfl_xor(pt0[i], m, 64);
            ps1[i] += __shfl_xor(ps1[i], m, 64);
            pt1[i] += __shfl_xor(pt1[i], m, 64);
        }
    }
    if (hl == 0) {
        int rbase0 = g0 * 16 + (lane >> 4) * 4;
        #pragma unroll
        for (int i = 0; i < 4; ++i) {
            s[rbase0 + i] = ps0[i];
            t[rbase0 + i] = pt0[i];
            if (g1ok) {
                s[rbase0 + 16 + i] = ps1[i];
                t[rbase0 + 16 + i] = pt1[i];
            }
        }
    }
}

// scalar mean-gather epilogue: out[i] = mean_j s[col] + t[i] + c
__global__ __launch_bounds__(256) void k_sagg2(const float* __restrict__ s,
                                               const float* __restrict__ t,
                                               const float* __restrict__ uvc,
                                               const int* __restrict__ rs,
                                               const int* __restrict__ col,
                                               float* __restrict__ out) {
    const int lane = threadIdx.x & 63;
    const int hl = lane & 15;
    const int node = blockIdx.x * 16 + (threadIdx.x >> 6) * 4 + (lane >> 4);
    const int j0 = rs[node], j1 = rs[node + 1];
    float sm = 0.f;
    for (int j = j0 + hl; j < j1; j += 16) sm += s[col[j]];
    #pragma unroll
    for (int m = 1; m < 16; m <<= 1) sm += __shfl_xor(sm, m, 64);
    if (hl == 0) {
        int deg = j1 - j0;
        out[node] = sm / (float)(deg > 0 ? deg : 1) + t[node] + uvc[256];
    }
}

// ---------------- launch ----------------

extern "C" void kernel_launch(void* const* d_in, const int* in_sizes, int n_in,
                              void* d_out, int out_size, void* d_ws,
                              size_t ws_size, hipStream_t stream) {
    const float* x = (const float*)d_in[0];
    const int* ei = (const int*)d_in[1];
    const int* src = ei;
    const int* dst = ei + N_EDGES;
    const float* wn[3] = {(const float*)d_in[2], (const float*)d_in[5],
                          (const float*)d_in[8]};
    const float* wr[3] = {(const float*)d_in[3], (const float*)d_in[6],
                          (const float*)d_in[9]};
    const float* bs[3] = {(const float*)d_in[4], (const float*)d_in[7],
                          (const float*)d_in[10]};
    const float* wc = (const float*)d_in[11];
    const float* bc = (const float*)d_in[12];
    float* out = (float*)d_out;

    char* ws = (char*)d_ws;
    size_t off = 0;
    auto alloc = [&](size_t bytes) -> void* {
        void* p = (void*)(ws + off);
        off += (bytes + 255) & ~(size_t)255;
        return p;
    };
    const size_t frows = (size_t)(N_NODES + 1) * D;
    int* bar = (int*)alloc(64);
    int* cnt = (int*)alloc((size_t)LTOT * 4);
    int* scC = (int*)alloc((size_t)LTOT * 4);
    int* psum = (int*)alloc(256 * 4);
    int2* epair = (int2*)alloc((size_t)N_EDGES * 8);
    int* rs = (int*)alloc((N_NODES + 1) * 4);
    int* col = (int*)alloc(N_EDGES * 4);
    unsigned short* f0 = (unsigned short*)alloc(frows * 2);
    unsigned short* f1 = (unsigned short*)alloc(frows * 2);
    unsigned short* f2 = (unsigned short*)alloc(frows * 2);
    unsigned short* Bp = (unsigned short*)alloc(2 * 256 * 128 * 2);
    float* uvc = (float*)alloc(260 * 4);
    float* sbuf = (float*)alloc(N_NODES * 4);
    float* tbuf = (float*)alloc(N_NODES * 4);

    hipMemsetAsync(bar, 0, 64, stream);  // barrier counters, re-zeroed per call

    k_mega<<<GRID_CSR, 256, 0, stream>>>(src, dst, bar, cnt, scC, psum, epair,
                                         rs, col, x, wn[0], wr[0], wn[1], wr[1],
                                         wn[2], wr[2], bs[2], wc, bc,
                                         f0, f1, f2, Bp, uvc);

    const int agg_grid = (N_NODES + 3) / 4;
    const int gemm_grid = ((NGROUPS + 1) / 2 + 3) / 4;
    unsigned short* Bp0 = Bp;
    unsigned short* Bp1 = Bp + 256 * 128;

    // layer 0: in=f0, mean=f1, out=f2 (relu)
    k_agg2<<<agg_grid, 256, 0, stream>>>(f0, rs, col, f1);
    k_gemm<<<gemm_grid, 256, 0, stream>>>(f1, f0, Bp0, bs[0], f2);
    // layer 1 (+ fused layer-2 dots): in=f2, mean=f0 -> s,t directly
    k_agg2<<<agg_grid, 256, 0, stream>>>(f2, rs, col, f0);
    k_gemm_dot<<<gemm_grid, 256, 0, stream>>>(f0, f2, Bp1, bs[1], uvc, sbuf,
                                              tbuf);
    // collapsed layer 2 + classifier: out = mean(s) + t + c
    k_sagg2<<<NGROUPS, 256, 0, stream>>>(sbuf, tbuf, uvc, rs, col, out);
}

// Round 15
// 134.704 us; speedup vs baseline: 3.3629x; 3.3629x over previous
//
#include <hip/hip_runtime.h>

#define N_NODES 50000
#define N_EDGES 800000
#define D 128
#define NGROUPS 3125   // N_NODES / 16
#define NBUK 256       // node buckets
#define NPB 196        // nodes per bucket (256*196 = 50176 >= 50001)
#define EPB 4096       // edges per histogram/scatter block (16/thread)
#define NBLK 196       // ceil(N_EDGES / EPB)
#define LTOT (NBUK * NBLK)  // 50176 scan cells
#define NSCB 49        // ceil(LTOT / 1024)

typedef __attribute__((ext_vector_type(8))) short short8;
typedef __attribute__((ext_vector_type(4))) float f32x4;

__device__ __forceinline__ float bits2f(unsigned int u) {
    union { unsigned int u; float f; } c; c.u = u; return c.f;
}
__device__ __forceinline__ unsigned short f2b(float f) {
    union { float f; unsigned int u; } c; c.f = f;
    unsigned int r = c.u + 0x7fffu + ((c.u >> 16) & 1u);
    return (unsigned short)(r >> 16);
}

// ---- mega-kernel 1: bucket-histogram | cast | pack W0,W1 | pad | u,v,c ----
// blocks [0,196):      LDS 256-bucket histogram of dst (4096 edges/block).
// blocks [196,6446):   cast x -> f0 (one float4/thread, 1.6M)
// blocks [6446,6478):  pack W0,W1 into MFMA B-frag order (8192 threads)
// block 6478:          zero pad row N_NODES of f0/f1/f2
// block 6479:          u = Wn2@wc, v = Wr2@wc, c = b2.wc + bc

__global__ __launch_bounds__(256) void k_big(
    const int* __restrict__ dst, int* __restrict__ cnt,
    const float* __restrict__ x,
    const float* __restrict__ wn0, const float* __restrict__ wr0,
    const float* __restrict__ wn1, const float* __restrict__ wr1,
    const float* __restrict__ wn2, const float* __restrict__ wr2,
    const float* __restrict__ b2, const float* __restrict__ wc,
    const float* __restrict__ bc,
    unsigned short* __restrict__ f0, unsigned short* __restrict__ f1,
    unsigned short* __restrict__ f2, unsigned short* __restrict__ Bp,
    float* __restrict__ uvc) {
    __shared__ int lc[NBUK];
    int b = blockIdx.x;
    int tid = threadIdx.x;
    if (b < NBLK) {
        lc[tid] = 0;
        __syncthreads();
        #pragma unroll
        for (int k = 0; k < 16; ++k) {
            int e = b * EPB + k * 256 + tid;
            if (e < N_EDGES) atomicAdd(&lc[dst[e] / NPB], 1);  // LDS atomic
        }
        __syncthreads();
        cnt[b * NBUK + tid] = lc[tid];
    } else if (b < 6446) {
        int i = (b - NBLK) * 256 + tid;
        float4 v = reinterpret_cast<const float4*>(x)[i];
        ushort4 o;
        o.x = f2b(v.x); o.y = f2b(v.y); o.z = f2b(v.z); o.w = f2b(v.w);
        reinterpret_cast<ushort4*>(f0)[i] = o;
    } else if (b < 6478) {
        int t = (b - 6446) * 256 + tid;  // exactly 8192 = 2*8*8*64
        int layer = t >> 12;
        int rem = t & 4095;
        int kstep = rem >> 9;
        int cf = (rem >> 6) & 7;
        int lane = t & 63;
        const float* W = (kstep < 4) ? (layer ? wn1 : wn0) : (layer ? wr1 : wr0);
        int kb = kstep * 32 + (lane >> 4) * 8;
        int colv = cf * 16 + (lane & 15);
        int koff = (kstep < 4) ? kb : kb - 128;
        unsigned short* dstp = Bp + (((layer * 64 + kstep * 8 + cf) * 64 + lane) << 3);
        #pragma unroll
        for (int i = 0; i < 8; ++i) dstp[i] = f2b(W[(koff + i) * D + colv]);
    } else if (b == 6478) {
        if (tid < D) {
            f0[(size_t)N_NODES * D + tid] = 0;
            f1[(size_t)N_NODES * D + tid] = 0;
            f2[(size_t)N_NODES * D + tid] = 0;
        }
    } else {
        if (tid < 128) {
            float su = 0.f;
            for (int m = 0; m < 128; ++m) su += wn2[tid * D + m] * wc[m];
            uvc[tid] = su;
        } else {
            int k = tid - 128;
            float sv = 0.f;
            for (int m = 0; m < 128; ++m) sv += wr2[k * D + m] * wc[m];
            uvc[128 + k] = sv;
        }
        if (tid == 0) {
            float sc0 = 0.f;
            for (int m = 0; m < 128; ++m) sc0 += b2[m] * wc[m];
            uvc[256] = sc0 + bc[0];
        }
    }
}

// ---- scanA: exclusive scan of cnt in bucket-major cell order -------------
// cell L = bucket*NBLK + block, value cnt[block*NBUK + bucket]. Validated
// r11 wave-scan structure (shfl + 16 wave-sums).

__global__ void k_scanA(const int* __restrict__ cnt, int* __restrict__ sc,
                        int* __restrict__ bsumA) {
    __shared__ int wsum[16];
    int tid = threadIdx.x;
    int lane = tid & 63, wid = tid >> 6;
    int L = blockIdx.x * 1024 + tid;
    int v = 0;
    if (L < LTOT) {
        int bkt = L / NBLK;
        int j = L - bkt * NBLK;
        v = cnt[j * NBUK + bkt];
    }
    int s = v;
    #pragma unroll
    for (int off = 1; off < 64; off <<= 1) {
        int t = __shfl_up(s, off, 64);
        if (lane >= off) s += t;
    }
    if (lane == 63) wsum[wid] = s;
    __syncthreads();
    if (tid < 64) {
        int wv = (tid < 16) ? wsum[tid] : 0;
        int t = wv;
        #pragma unroll
        for (int off = 1; off < 16; off <<= 1) {
            int u = __shfl_up(t, off, 64);
            if (tid >= off) t += u;
        }
        if (tid < 16) wsum[tid] = t - wv;
    }
    __syncthreads();
    int excl = s - v + wsum[wid];
    if (L < LTOT) sc[L] = excl;
    if (tid == 1023) bsumA[blockIdx.x] = excl + v;
}

// ---- scatter: group edges by bucket via LDS cursors ----------------------
// Block j re-reads its 4096 edges; cursor[b] starts at the global offset of
// cell (b, j); claims are LDS atomics. Writes int2{dst,src} bucket-grouped.

__global__ __launch_bounds__(256) void k_scatter(
    const int* __restrict__ src, const int* __restrict__ dst,
    const int* __restrict__ sc, const int* __restrict__ bsumA,
    int2* __restrict__ epair) {
    __shared__ int sb[64];
    __shared__ int cursor[NBUK];
    int tid = threadIdx.x, j = blockIdx.x;
    if (tid < 64) sb[tid] = (tid < NSCB) ? bsumA[tid] : 0;
    __syncthreads();
    for (int off = 1; off < 64; off <<= 1) {  // LDS Hillis-Steele (validated)
        int t = (tid < 64 && tid >= off) ? sb[tid - off] : 0;
        __syncthreads();
        if (tid < 64) sb[tid] += t;
        __syncthreads();
    }
    int L = tid * NBLK + j;
    int idx = L >> 10;
    cursor[tid] = sc[L] + (idx ? sb[idx - 1] : 0);
    __syncthreads();
    #pragma unroll
    for (int k = 0; k < 16; ++k) {
        int e = j * EPB + k * 256 + tid;
        if (e < N_EDGES) {
            int d = dst[e];
            int p = atomicAdd(&cursor[d / NPB], 1);  // LDS atomic
            epair[p] = make_int2(d, src[e]);
        }
    }
}

// ---- bucket: per-bucket rank + rs + final col (replaces scan + fill) -----
// One block per bucket (~3.1k edges, 196 nodes): LDS count -> LDS scan ->
// rs writes -> LDS-cursor scatter into col. All atomics are LDS.

__global__ __launch_bounds__(256) void k_bucket(
    const int* __restrict__ sc, const int* __restrict__ bsumA,
    const int2* __restrict__ epair,
    int* __restrict__ rs, int* __restrict__ col) {
    __shared__ int sb[64];
    __shared__ int lcnt[NPB];
    __shared__ int s2[256];
    __shared__ int cur[NPB];
    int tid = threadIdx.x, b = blockIdx.x;
    if (tid < 64) sb[tid] = (tid < NSCB) ? bsumA[tid] : 0;
    __syncthreads();
    for (int off = 1; off < 64; off <<= 1) {
        int t = (tid < 64 && tid >= off) ? sb[tid - off] : 0;
        __syncthreads();
        if (tid < 64) sb[tid] += t;
        __syncthreads();
    }
    int L0 = b * NBLK;
    int i0 = L0 >> 10;
    int gstart = sc[L0] + (i0 ? sb[i0 - 1] : 0);
    int bend = N_EDGES;
    if (b + 1 < NBUK) {
        int L1 = (b + 1) * NBLK;
        int i1 = L1 >> 10;
        bend = sc[L1] + (i1 ? sb[i1 - 1] : 0);
    }
    if (tid < NPB) lcnt[tid] = 0;
    __syncthreads();
    for (int e = gstart + tid; e < bend; e += 256)
        atomicAdd(&lcnt[epair[e].x - b * NPB], 1);  // LDS atomic
    __syncthreads();
    int v = (tid < NPB) ? lcnt[tid] : 0;
    s2[tid] = v;
    __syncthreads();
    for (int off = 1; off < 256; off <<= 1) {
        int t = (tid >= off) ? s2[tid - off] : 0;
        __syncthreads();
        s2[tid] += t;
        __syncthreads();
    }
    int excl = s2[tid] - v;
    int node = b * NPB + tid;
    if (tid < NPB) {
        if (node <= N_NODES) rs[node] = gstart + excl;
        cur[tid] = gstart + excl;
    }
    __syncthreads();
    for (int e = gstart + tid; e < bend; e += 256) {
        int2 p2 = epair[e];
        int p = atomicAdd(&cur[p2.x - b * NPB], 1);  // LDS atomic
        col[p] = p2.y;
    }
    if (b == NBUK - 1 && tid == 0) rs[N_NODES] = N_EDGES;
}

// ---------------- mean aggregation: one node per wave (validated r8) ------

#define ACCUM(v)                                                      \
    acc0 += bits2f((v).x << 16); acc1 += bits2f((v).x & 0xffff0000u); \
    acc2 += bits2f((v).y << 16); acc3 += bits2f((v).y & 0xffff0000u); \
    acc4 += bits2f((v).z << 16); acc5 += bits2f((v).z & 0xffff0000u); \
    acc6 += bits2f((v).w << 16); acc7 += bits2f((v).w & 0xffff0000u);

__global__ __launch_bounds__(256) void k_agg2(const unsigned short* __restrict__ h,
                                              const int* __restrict__ rs,
                                              const int* __restrict__ col,
                                              unsigned short* __restrict__ mean) {
    const int lane = threadIdx.x & 63;
    const int node = blockIdx.x * 4 + (threadIdx.x >> 6);
    if (node >= N_NODES) return;
    const int j0 = rs[node], j1 = rs[node + 1];
    const int deg = j1 - j0;
    const int q = lane >> 4;
    const int d8 = (lane & 15) * 8;

    int myc = (j0 + lane < j1) ? col[j0 + lane] : N_NODES;  // pad row: zeros
    const int nfull = deg < 64 ? deg : 64;
    const int nb = (nfull + 15) >> 4;   // wave-uniform batch count

    float acc0 = 0.f, acc1 = 0.f, acc2 = 0.f, acc3 = 0.f;
    float acc4 = 0.f, acc5 = 0.f, acc6 = 0.f, acc7 = 0.f;

    for (int i = 0; i < nb; ++i) {      // uniform trips: shfl always safe
        int t = (i << 4) + q;
        int c0 = __shfl(myc, t, 64);
        int c1 = __shfl(myc, t + 4, 64);
        int c2 = __shfl(myc, t + 8, 64);
        int c3 = __shfl(myc, t + 12, 64);
        uint4 v0 = *(const uint4*)(h + (size_t)c0 * D + d8);
        uint4 v1 = *(const uint4*)(h + (size_t)c1 * D + d8);
        uint4 v2 = *(const uint4*)(h + (size_t)c2 * D + d8);
        uint4 v3 = *(const uint4*)(h + (size_t)c3 * D + d8);
        ACCUM(v0); ACCUM(v1); ACCUM(v2); ACCUM(v3);
    }
    for (int j = j0 + 64 + q; j < j1; j += 4) {  // deg>64 (~never); no shfl
        int c = col[j];
        uint4 v = *(const uint4*)(h + (size_t)c * D + d8);
        ACCUM(v);
    }

    acc0 += __shfl_xor(acc0, 16, 64); acc0 += __shfl_xor(acc0, 32, 64);
    acc1 += __shfl_xor(acc1, 16, 64); acc1 += __shfl_xor(acc1, 32, 64);
    acc2 += __shfl_xor(acc2, 16, 64); acc2 += __shfl_xor(acc2, 32, 64);
    acc3 += __shfl_xor(acc3, 16, 64); acc3 += __shfl_xor(acc3, 32, 64);
    acc4 += __shfl_xor(acc4, 16, 64); acc4 += __shfl_xor(acc4, 32, 64);
    acc5 += __shfl_xor(acc5, 16, 64); acc5 += __shfl_xor(acc5, 32, 64);
    acc6 += __shfl_xor(acc6, 16, 64); acc6 += __shfl_xor(acc6, 32, 64);
    acc7 += __shfl_xor(acc7, 16, 64); acc7 += __shfl_xor(acc7, 32, 64);

    if (lane < 16) {
        float s = 1.0f / (float)(deg > 0 ? deg : 1);
        uint4 o;
        o.x = (unsigned int)f2b(acc0 * s) | ((unsigned int)f2b(acc1 * s) << 16);
        o.y = (unsigned int)f2b(acc2 * s) | ((unsigned int)f2b(acc3 * s) << 16);
        o.z = (unsigned int)f2b(acc4 * s) | ((unsigned int)f2b(acc5 * s) << 16);
        o.w = (unsigned int)f2b(acc6 * s) | ((unsigned int)f2b(acc7 * s) << 16);
        *reinterpret_cast<uint4*>(mean + (size_t)node * D + d8) = o;
    }
}

// ---------------- MFMA GEMM (relu, layer 0): 2 row-groups per wave --------

__global__ __launch_bounds__(256) void k_gemm(
    const unsigned short* __restrict__ Amean, const unsigned short* __restrict__ Ah,
    const unsigned short* __restrict__ Bp, const float* __restrict__ bias,
    unsigned short* __restrict__ outh) {
    int lane = threadIdx.x & 63;
    int w = blockIdx.x * 4 + (threadIdx.x >> 6);
    int g0 = w * 2;
    if (g0 >= NGROUPS) return;
    int g1ok = (g0 + 1 < NGROUPS);
    int hl = lane & 15;
    int klane = (lane >> 4) * 8;
    int arow0 = g0 * 16 + hl;
    int arow1 = g0 * 16 + 16 + hl;
    if (arow1 > N_NODES) arow1 = N_NODES;  // pad row (zeros) when g1 invalid

    f32x4 acc0[8], acc1[8];
    #pragma unroll
    for (int i = 0; i < 8; ++i) { acc0[i] = (f32x4)0.0f; acc1[i] = (f32x4)0.0f; }

    const short8* bpv = reinterpret_cast<const short8*>(Bp);
    #pragma unroll
    for (int kstep = 0; kstep < 8; ++kstep) {
        const unsigned short* Asrc = (kstep < 4) ? Amean : Ah;
        int kk = (kstep & 3) * 32 + klane;
        short8 a0 = *reinterpret_cast<const short8*>(Asrc + (size_t)arow0 * D + kk);
        short8 a1 = *reinterpret_cast<const short8*>(Asrc + (size_t)arow1 * D + kk);
        #pragma unroll
        for (int cf = 0; cf < 8; ++cf) {
            short8 b = bpv[(kstep * 8 + cf) * 64 + lane];
            acc0[cf] = __builtin_amdgcn_mfma_f32_16x16x32_bf16(a0, b, acc0[cf], 0, 0, 0);
            acc1[cf] = __builtin_amdgcn_mfma_f32_16x16x32_bf16(a1, b, acc1[cf], 0, 0, 0);
        }
    }

    int rbase0 = g0 * 16 + (lane >> 4) * 4;
    #pragma unroll
    for (int cf = 0; cf < 8; ++cf) {
        int bcol = cf * 16 + hl;
        float bv = bias[bcol];
        #pragma unroll
        for (int i = 0; i < 4; ++i) {
            float v = fmaxf(acc0[cf][i] + bv, 0.f);
            outh[(size_t)(rbase0 + i) * D + bcol] = f2b(v);
            if (g1ok) {
                float v1 = fmaxf(acc1[cf][i] + bv, 0.f);
                outh[(size_t)(rbase0 + 16 + i) * D + bcol] = f2b(v1);
            }
        }
    }
}

// ---- MFMA GEMM layer 1 + fused dot: s = relu(row).u, t = relu(row).v -----

__global__ __launch_bounds__(256) void k_gemm_dot(
    const unsigned short* __restrict__ Amean, const unsigned short* __restrict__ Ah,
    const unsigned short* __restrict__ Bp, const float* __restrict__ bias,
    const float* __restrict__ uvc, float* __restrict__ s, float* __restrict__ t) {
    int lane = threadIdx.x & 63;
    int w = blockIdx.x * 4 + (threadIdx.x >> 6);
    int g0 = w * 2;
    if (g0 >= NGROUPS) return;
    int g1ok = (g0 + 1 < NGROUPS);
    int hl = lane & 15;
    int klane = (lane >> 4) * 8;
    int arow0 = g0 * 16 + hl;
    int arow1 = g0 * 16 + 16 + hl;
    if (arow1 > N_NODES) arow1 = N_NODES;

    f32x4 acc0[8], acc1[8];
    #pragma unroll
    for (int i = 0; i < 8; ++i) { acc0[i] = (f32x4)0.0f; acc1[i] = (f32x4)0.0f; }

    const short8* bpv = reinterpret_cast<const short8*>(Bp);
    #pragma unroll
    for (int kstep = 0; kstep < 8; ++kstep) {
        const unsigned short* Asrc = (kstep < 4) ? Amean : Ah;
        int kk = (kstep & 3) * 32 + klane;
        short8 a0 = *reinterpret_cast<const short8*>(Asrc + (size_t)arow0 * D + kk);
        short8 a1 = *reinterpret_cast<const short8*>(Asrc + (size_t)arow1 * D + kk);
        #pragma unroll
        for (int cf = 0; cf < 8; ++cf) {
            short8 b = bpv[(kstep * 8 + cf) * 64 + lane];
            acc0[cf] = __builtin_amdgcn_mfma_f32_16x16x32_bf16(a0, b, acc0[cf], 0, 0, 0);
            acc1[cf] = __builtin_amdgcn_mfma_f32_16x16x32_bf16(a1, b, acc1[cf], 0, 0, 0);
        }
    }

    float ps0[4] = {0.f, 0.f, 0.f, 0.f}, pt0[4] = {0.f, 0.f, 0.f, 0.f};
    float ps1[4] = {0.f, 0.f, 0.f, 0.f}, pt1[4] = {0.f, 0.f, 0.f, 0.f};
    #pragma unroll
    for (int cf = 0; cf < 8; ++cf) {
        int bcol = cf * 16 + hl;
        float bv = bias[bcol];
        float uu = uvc[bcol];
        float vv = uvc[128 + bcol];
        #pragma unroll
        for (int i = 0; i < 4; ++i) {
            float v = fmaxf(acc0[cf][i] + bv, 0.f);
            ps0[i] += v * uu;
            pt0[i] += v * vv;
            float v1 = fmaxf(acc1[cf][i] + bv, 0.f);
            ps1[i] += v1 * uu;
            pt1[i] += v1 * vv;
        }
    }
    #pragma unroll
    for (int m = 1; m < 16; m <<= 1) {
        #pragma unroll
        for (int i = 0; i < 4; ++i) {
            ps0[i] += __shfl_xor(ps0[i], m, 64);
            pt0[i] += __shfl_xor(pt0[i], m, 64);
            ps1[i] += __shfl_xor(ps1[i], m, 64);
            pt1[i] += __shfl_xor(pt1[i], m, 64);
        }
    }
    if (hl == 0) {
        int rbase0 = g0 * 16 + (lane >> 4) * 4;
        #pragma unroll
        for (int i = 0; i < 4; ++i) {
            s[rbase0 + i] = ps0[i];
            t[rbase0 + i] = pt0[i];
            if (g1ok) {
                s[rbase0 + 16 + i] = ps1[i];
                t[rbase0 + 16 + i] = pt1[i];
            }
        }
    }
}

// scalar mean-gather epilogue: out[i] = mean_j s[col] + t[i] + c
__global__ __launch_bounds__(256) void k_sagg2(const float* __restrict__ s,
                                               const float* __restrict__ t,
                                               const float* __restrict__ uvc,
                                               const int* __restrict__ rs,
                                               const int* __restrict__ col,
                                               float* __restrict__ out) {
    const int lane = threadIdx.x & 63;
    const int hl = lane & 15;
    const int node = blockIdx.x * 16 + (threadIdx.x >> 6) * 4 + (lane >> 4);
    const int j0 = rs[node], j1 = rs[node + 1];
    float sm = 0.f;
    for (int j = j0 + hl; j < j1; j += 16) sm += s[col[j]];
    #pragma unroll
    for (int m = 1; m < 16; m <<= 1) sm += __shfl_xor(sm, m, 64);
    if (hl == 0) {
        int deg = j1 - j0;
        out[node] = sm / (float)(deg > 0 ? deg : 1) + t[node] + uvc[256];
    }
}

// ---------------- launch ----------------

extern "C" void kernel_launch(void* const* d_in, const int* in_sizes, int n_in,
                              void* d_out, int out_size, void* d_ws,
                              size_t ws_size, hipStream_t stream) {
    const float* x = (const float*)d_in[0];
    const int* ei = (const int*)d_in[1];
    const int* src = ei;
    const int* dst = ei + N_EDGES;
    const float* wn[3] = {(const float*)d_in[2], (const float*)d_in[5],
                          (const float*)d_in[8]};
    const float* wr[3] = {(const float*)d_in[3], (const float*)d_in[6],
                          (const float*)d_in[9]};
    const float* bs[3] = {(const float*)d_in[4], (const float*)d_in[7],
                          (const float*)d_in[10]};
    const float* wc = (const float*)d_in[11];
    const float* bc = (const float*)d_in[12];
    float* out = (float*)d_out;

    char* ws = (char*)d_ws;
    size_t off = 0;
    auto alloc = [&](size_t bytes) -> void* {
        void* p = (void*)(ws + off);
        off += (bytes + 255) & ~(size_t)255;
        return p;
    };
    const size_t frows = (size_t)(N_NODES + 1) * D;
    int* cnt = (int*)alloc((size_t)LTOT * 4);      // [NBLK][NBUK]
    int* sc = (int*)alloc((size_t)LTOT * 4);       // scanned cells
    int* bsumA = (int*)alloc(64 * 4);
    int2* epair = (int2*)alloc((size_t)N_EDGES * 8);  // bucket-grouped {dst,src}
    int* rs = (int*)alloc((N_NODES + 1) * 4);
    int* col = (int*)alloc(N_EDGES * 4);
    unsigned short* f0 = (unsigned short*)alloc(frows * 2);
    unsigned short* f1 = (unsigned short*)alloc(frows * 2);
    unsigned short* f2 = (unsigned short*)alloc(frows * 2);
    unsigned short* Bp = (unsigned short*)alloc(2 * 256 * 128 * 2);
    float* uvc = (float*)alloc(260 * 4);
    float* sbuf = (float*)alloc(N_NODES * 4);
    float* tbuf = (float*)alloc(N_NODES * 4);

    // no memsets: cnt fully written by k_big; LDS counters zeroed in-kernel

    k_big<<<6480, 256, 0, stream>>>(dst, cnt, x, wn[0], wr[0], wn[1], wr[1],
                                    wn[2], wr[2], bs[2], wc, bc,
                                    f0, f1, f2, Bp, uvc);
    k_scanA<<<NSCB, 1024, 0, stream>>>(cnt, sc, bsumA);
    k_scatter<<<NBLK, 256, 0, stream>>>(src, dst, sc, bsumA, epair);
    k_bucket<<<NBUK, 256, 0, stream>>>(sc, bsumA, epair, rs, col);

    const int agg_grid = (N_NODES + 3) / 4;
    const int gemm_grid = ((NGROUPS + 1) / 2 + 3) / 4;
    unsigned short* Bp0 = Bp;
    unsigned short* Bp1 = Bp + 256 * 128;

    // layer 0: in=f0, mean=f1, out=f2 (relu)
    k_agg2<<<agg_grid, 256, 0, stream>>>(f0, rs, col, f1);
    k_gemm<<<gemm_grid, 256, 0, stream>>>(f1, f0, Bp0, bs[0], f2);
    // layer 1 (+ fused layer-2 dots): in=f2, mean=f0 -> s,t directly
    k_agg2<<<agg_grid, 256, 0, stream>>>(f2, rs, col, f0);
    k_gemm_dot<<<gemm_grid, 256, 0, stream>>>(f0, f2, Bp1, bs[1], uvc, sbuf,
                                              tbuf);
    // collapsed layer 2 + classifier: out = mean(s) + t + c
    k_sagg2<<<NGROUPS, 256, 0, stream>>>(sbuf, tbuf, uvc, rs, col, out);
}